// Round 3
// baseline (174.145 us; speedup 1.0000x reference)
//
#include <hip/hip_runtime.h>

typedef unsigned short ushort_t;
typedef short bf16x8 __attribute__((ext_vector_type(8)));
typedef float fp32x4 __attribute__((ext_vector_type(4)));

#define BS 4096
#define NROW 8192
#define D 512
#define TILE 128
#define BK 32
#define NB (NROW / TILE)          // 64 block-rows/cols
#define NBLK (NB * (NB + 1) / 2)  // 2080 upper-triangle blocks (= 8 * 260)
#define PERXCD (NBLK / 8)         // 260
#define INV_T 10.0f

__device__ __forceinline__ unsigned short f2bf(float f) {
  unsigned int u = __float_as_uint(f);
  u += 0x7fffu + ((u >> 16) & 1u);
  return (unsigned short)(u >> 16);
}

__device__ __forceinline__ void g2l16(const void* g, void* l) {
  __builtin_amdgcn_global_load_lds(
      (const __attribute__((address_space(1))) unsigned int*)g,
      (__attribute__((address_space(3))) unsigned int*)l, 16, 0, 0);
}

// Wave-per-row normalize: block = 4 waves = 4 rows. Also zeroes den/posAcc
// (harness re-poisons ws every launch; no separate memset dispatch needed).
__global__ __launch_bounds__(256) void normalize_k(
    const float* __restrict__ zi, const float* __restrict__ zj,
    ushort_t* __restrict__ An, float* __restrict__ den,
    float* __restrict__ posAcc) {
  const int lane = threadIdx.x & 63;
  const int wave = threadIdx.x >> 6;
  const int r = blockIdx.x * 4 + wave;
  const float* src = (r < BS) ? (zi + (size_t)r * D) : (zj + (size_t)(r - BS) * D);
  const float4 v0 = ((const float4*)src)[lane];
  const float4 v1 = ((const float4*)src)[lane + 64];
  float ss = v0.x * v0.x + v0.y * v0.y + v0.z * v0.z + v0.w * v0.w +
             v1.x * v1.x + v1.y * v1.y + v1.z * v1.z + v1.w * v1.w;
#pragma unroll
  for (int off = 1; off < 64; off <<= 1) ss += __shfl_xor(ss, off);
  const float inv = 1.0f / fmaxf(sqrtf(ss), 1e-8f);
  ushort4 o0, o1;
  o0.x = f2bf(v0.x * inv); o0.y = f2bf(v0.y * inv);
  o0.z = f2bf(v0.z * inv); o0.w = f2bf(v0.w * inv);
  o1.x = f2bf(v1.x * inv); o1.y = f2bf(v1.y * inv);
  o1.z = f2bf(v1.z * inv); o1.w = f2bf(v1.w * inv);
  ushort4* dst = (ushort4*)(An + (size_t)r * D);
  dst[lane] = o0;
  dst[lane + 64] = o1;
  if (lane == 0) den[r] = 0.0f;
  if (r == 0 && lane == 0) posAcc[0] = 0.0f;
}

// Upper-triangle (bi<=bj) 128x128 tiles of sim = An*An^T, double-buffered LDS.
// Off-diagonal tiles: den[row] += rowsum(exp), den[col] += colsum(exp).
// Diagonal tiles: den[row] += rowsum(exp), row==col masked.
// posAcc += sim/T over entries col == row+BS (upper copy; doubled in finalize).
__global__ __launch_bounds__(256) void gemm_expsum(
    const ushort_t* __restrict__ An, float* __restrict__ den,
    float* __restrict__ posAcc) {
  __shared__ __align__(16) ushort_t sA[2][TILE * BK];
  __shared__ __align__(16) ushort_t sB[2][TILE * BK];

  // XCD-locality swizzle: blocks with bid%8==k presumably land on XCD k;
  // give each XCD a contiguous row-major band of the triangle so its A
  // row-groups stay resident in its 4 MB L2.
  const int t = (blockIdx.x >> 3) + (blockIdx.x & 7) * PERXCD;
  int rem = t;
  int bi = 0;
  while (rem >= NB - bi) { rem -= NB - bi; ++bi; }
  const int bj = bi + rem;
  const bool diag = (bi == bj);
  const int rowBase = bi * TILE;
  const int colBase = bj * TILE;

  const int tid = threadIdx.x;
  const int lane = tid & 63;
  const int wave = tid >> 6;
  const int wr = wave >> 1;
  const int wc = wave & 1;

  fp32x4 acc[4][4] = {};

  // staging: 512 16B chunks per tile; thread handles chunks tid and tid+256.
  // LDS slot c holds global chunk (row = c>>2, q = (c&3) ^ ((row>>1)&3)):
  // XOR-swizzle keeps ds_read_b128 at 2-way (free) instead of 8-way conflict.
  const int c0 = tid;
  const int c1 = tid + 256;
  const int r0 = c0 >> 2, q0 = (c0 & 3) ^ ((r0 >> 1) & 3);
  const int r1 = c1 >> 2, q1 = (c1 & 3) ^ ((r1 >> 1) & 3);
  const ushort_t* gA0 = An + (size_t)(rowBase + r0) * D + q0 * 8;
  const ushort_t* gA1 = An + (size_t)(rowBase + r1) * D + q1 * 8;
  const ushort_t* gB0 = An + (size_t)(colBase + r0) * D + q0 * 8;
  const ushort_t* gB1 = An + (size_t)(colBase + r1) * D + q1 * 8;

  const int fr = lane & 15;  // A row / B col within 16-tile
  const int q = lane >> 4;   // k quad index (0..3), 8 elems each

  // Prologue: stage tile k=0 into buffer 0.
  g2l16(gA0, sA[0] + c0 * 8);
  g2l16(gA1, sA[0] + c1 * 8);
  g2l16(gB0, sB[0] + c0 * 8);
  g2l16(gB1, sB[0] + c1 * 8);

  int cur = 0;
  for (int k0 = 0; k0 < D; k0 += BK, cur ^= 1) {
    // Barrier drains vmcnt(0): buf[cur] staging complete; all waves have
    // finished reading buf[cur^1] (previous iteration's compute).
    __syncthreads();
    const int nk = k0 + BK;
    if (nk < D) {
      // Issue next tile's staging NOW — its vmcnt drain happens at the NEXT
      // barrier, overlapping the ds_read + 16 MFMA below.
      g2l16(gA0 + nk, sA[cur ^ 1] + c0 * 8);
      g2l16(gA1 + nk, sA[cur ^ 1] + c1 * 8);
      g2l16(gB0 + nk, sB[cur ^ 1] + c0 * 8);
      g2l16(gB1 + nk, sB[cur ^ 1] + c1 * 8);
    }
    bf16x8 a[4], b[4];
#pragma unroll
    for (int i = 0; i < 4; ++i) {
      const int ra = wr * 64 + i * 16 + fr;
      const int rb = wc * 64 + i * 16 + fr;
      a[i] = *(const bf16x8*)(sA[cur] + ra * BK + ((q ^ ((ra >> 1) & 3)) * 8));
      b[i] = *(const bf16x8*)(sB[cur] + rb * BK + ((q ^ ((rb >> 1) & 3)) * 8));
    }
#pragma unroll
    for (int i = 0; i < 4; ++i)
#pragma unroll
      for (int j = 0; j < 4; ++j)
        acc[i][j] =
            __builtin_amdgcn_mfma_f32_16x16x32_bf16(a[i], b[j], acc[i][j], 0, 0, 0);
  }

  // Epilogue. C/D layout (16x16x32): col = lane&15, row = (lane>>4)*4 + reg.
  const int rq = q * 4;
  float posPart = 0.0f;
  float colAcc[4] = {0.0f, 0.0f, 0.0f, 0.0f};
#pragma unroll
  for (int i = 0; i < 4; ++i) {
    const int rbase = rowBase + wr * 64 + i * 16 + rq;
    float rs[4] = {0.0f, 0.0f, 0.0f, 0.0f};
#pragma unroll
    for (int j = 0; j < 4; ++j) {
      const int colg = colBase + wc * 64 + j * 16 + fr;
      fp32x4 v = acc[i][j];
#pragma unroll
      for (int rg = 0; rg < 4; ++rg) {
        const int rowg = rbase + rg;
        const float sv = v[rg] * INV_T;
        float e = __expf(sv);
        if (diag && rowg == colg) e = 0.0f;  // exclude matrix diagonal exactly
        rs[rg] += e;
        colAcc[j] += e;
        if (colg == rowg + BS) posPart += sv;  // upper copy only; doubled later
      }
    }
    // row sums: reduce over the 16 columns (lanes differing in bits 0..3)
#pragma unroll
    for (int rg = 0; rg < 4; ++rg) {
      float s = rs[rg];
      s += __shfl_xor(s, 1);
      s += __shfl_xor(s, 2);
      s += __shfl_xor(s, 4);
      s += __shfl_xor(s, 8);
      if (fr == 0) atomicAdd(&den[rbase + rg], s);
    }
  }
  if (!diag) {
    // col sums (symmetric contribution): regs already summed; reduce lanes
    // differing in bits 4..5
#pragma unroll
    for (int j = 0; j < 4; ++j) {
      float c = colAcc[j];
      c += __shfl_xor(c, 16);
      c += __shfl_xor(c, 32);
      if (q == 0) atomicAdd(&den[colBase + wc * 64 + j * 16 + fr], c);
    }
  }
  posPart += __shfl_xor(posPart, 1);
  posPart += __shfl_xor(posPart, 2);
  posPart += __shfl_xor(posPart, 4);
  posPart += __shfl_xor(posPart, 8);
  posPart += __shfl_xor(posPart, 16);
  posPart += __shfl_xor(posPart, 32);
  if (lane == 0 && posPart != 0.0f) atomicAdd(posAcc, posPart);
}

__global__ __launch_bounds__(256) void finalize_k(
    const float* __restrict__ den, const float* __restrict__ posAcc,
    float* __restrict__ out) {
  const int t = threadIdx.x;
  float s = 0.0f;
  for (int i = t; i < NROW; i += 256) s += logf(den[i]);
#pragma unroll
  for (int off = 1; off < 64; off <<= 1) s += __shfl_xor(s, off);
  __shared__ float ws[4];
  if ((t & 63) == 0) ws[t >> 6] = s;
  __syncthreads();
  if (t == 0) {
    const float tot = ws[0] + ws[1] + ws[2] + ws[3];
    // each unordered positive pair was counted once -> double it
    out[0] = (tot - 2.0f * posAcc[0]) * (1.0f / (float)NROW);
  }
}

extern "C" void kernel_launch(void* const* d_in, const int* in_sizes, int n_in,
                              void* d_out, int out_size, void* d_ws, size_t ws_size,
                              hipStream_t stream) {
  const float* zi = (const float*)d_in[0];
  const float* zj = (const float*)d_in[1];
  float* out = (float*)d_out;

  ushort_t* An = (ushort_t*)d_ws;                             // 8 MB bf16 normalized reps
  float* den = (float*)((char*)d_ws + (size_t)NROW * D * 2);  // 8192 fp32
  float* posAcc = den + NROW;                                 // 1 fp32

  normalize_k<<<NROW / 4, 256, 0, stream>>>(zi, zj, An, den, posAcc);
  gemm_expsum<<<NBLK, 256, 0, stream>>>(An, den, posAcc);
  finalize_k<<<1, 256, 0, stream>>>(den, posAcc, out);
}

// Round 4
// 139.583 us; speedup vs baseline: 1.2476x; 1.2476x over previous
//
#include <hip/hip_runtime.h>

typedef unsigned char u8;
typedef float fp32x4 __attribute__((ext_vector_type(4)));

#define BS 4096
#define NROW 8192
#define D 512
#define TILE 128
#define BK 64                     // k-elems (= bytes, fp8) staged per iter
#define NB (NROW / TILE)          // 64 block-rows/cols
#define NBLK (NB * (NB + 1) / 2)  // 2080 upper-triangle blocks
#define INV_T 10.0f

__device__ __forceinline__ void g2l16(const void* g, void* l) {
  __builtin_amdgcn_global_load_lds(
      (const __attribute__((address_space(1))) unsigned int*)g,
      (__attribute__((address_space(3))) unsigned int*)l, 16, 0, 0);
}

// Wave-per-row normalize -> fp8 e4m3 output (An is 4 MB: fits one XCD L2).
// Also zeroes den/posAcc (ws is re-poisoned before every launch).
__global__ __launch_bounds__(256) void normalize_k(
    const float* __restrict__ zi, const float* __restrict__ zj,
    u8* __restrict__ An, float* __restrict__ den, float* __restrict__ posAcc) {
  const int lane = threadIdx.x & 63;
  const int wave = threadIdx.x >> 6;
  const int r = blockIdx.x * 4 + wave;
  const float* src = (r < BS) ? (zi + (size_t)r * D) : (zj + (size_t)(r - BS) * D);
  const float4 v0 = ((const float4*)src)[lane * 2];
  const float4 v1 = ((const float4*)src)[lane * 2 + 1];
  float ss = v0.x * v0.x + v0.y * v0.y + v0.z * v0.z + v0.w * v0.w +
             v1.x * v1.x + v1.y * v1.y + v1.z * v1.z + v1.w * v1.w;
#pragma unroll
  for (int off = 1; off < 64; off <<= 1) ss += __shfl_xor(ss, off);
  const float inv = 1.0f / fmaxf(sqrtf(ss), 1e-8f);
  int lo = __builtin_amdgcn_cvt_pk_fp8_f32(v0.x * inv, v0.y * inv, 0, false);
  lo = __builtin_amdgcn_cvt_pk_fp8_f32(v0.z * inv, v0.w * inv, lo, true);
  int hi = __builtin_amdgcn_cvt_pk_fp8_f32(v1.x * inv, v1.y * inv, 0, false);
  hi = __builtin_amdgcn_cvt_pk_fp8_f32(v1.z * inv, v1.w * inv, hi, true);
  ((int2*)(An + (size_t)r * D))[lane] = make_int2(lo, hi);
  if (lane == 0) den[r] = 0.0f;
  if (r == 0 && lane == 0) posAcc[0] = 0.0f;
}

// Upper-triangle (bi<=bj) 128x128 tiles of sim = An*An^T, fp8 MFMA, single
// 16 KB LDS buffer, R2's 2-barrier K-loop (TLP does the latency hiding).
// Off-diagonal tiles: den[row] += rowsum(exp), den[col] += colsum(exp).
// Diagonal tiles: den[row] += rowsum(exp), row==col masked.
// posAcc += sim/T over entries col == row+BS (upper copy; doubled in finalize).
__global__ __launch_bounds__(256) void gemm_expsum(
    const u8* __restrict__ An, float* __restrict__ den,
    float* __restrict__ posAcc) {
  __shared__ __align__(16) u8 sA[TILE * BK];  // 8 KB
  __shared__ __align__(16) u8 sB[TILE * BK];  // 8 KB

  // linear triangle order: consecutive blocks share the A-strip (L2 reuse)
  int rem = blockIdx.x;
  int bi = 0;
  while (rem >= NB - bi) { rem -= NB - bi; ++bi; }
  const int bj = bi + rem;
  const bool diag = (bi == bj);
  const int rowBase = bi * TILE;
  const int colBase = bj * TILE;

  const int tid = threadIdx.x;
  const int lane = tid & 63;
  const int wave = tid >> 6;
  const int wr = wave >> 1;
  const int wc = wave & 1;

  fp32x4 acc[4][4] = {};

  // staging: 512 16B chunks per tile (row = c>>2, 4 chunks of 16 k-bytes per
  // row); LDS slot c holds global chunk ((c&3) ^ ((row>>1)&3)) — XOR swizzle
  // keeps the ds_read bank pattern at the free 2-way aliasing level.
  const int c0 = tid;
  const int c1 = tid + 256;
  const int r0 = c0 >> 2, q0 = (c0 & 3) ^ ((r0 >> 1) & 3);
  const int r1 = c1 >> 2, q1 = (c1 & 3) ^ ((r1 >> 1) & 3);
  const u8* gA0 = An + (size_t)(rowBase + r0) * D + q0 * 16;
  const u8* gA1 = An + (size_t)(rowBase + r1) * D + q1 * 16;
  const u8* gB0 = An + (size_t)(colBase + r0) * D + q0 * 16;
  const u8* gB1 = An + (size_t)(colBase + r1) * D + q1 * 16;
  u8* lA0 = sA + c0 * 16;
  u8* lA1 = sA + c1 * 16;
  u8* lB0 = sB + c0 * 16;
  u8* lB1 = sB + c1 * 16;

  const int fr = lane & 15;       // A row / B col within 16-tile
  const int h = lane >> 4;        // 0..3
  const int w8 = (h & 1) * 8;     // byte offset within 16B chunk
  const int qh = h >> 1;          // chunk half-index for sub-iter 0

  for (int k0 = 0; k0 < D; k0 += BK) {
    g2l16(gA0 + k0, lA0);
    g2l16(gA1 + k0, lA1);
    g2l16(gB0 + k0, lB0);
    g2l16(gB1 + k0, lB1);
    __syncthreads();  // drains vmcnt -> LDS tiles complete
    // two K=32 fp8 MFMA sub-iterations per staged BK=64
#pragma unroll
    for (int sub = 0; sub < 2; ++sub) {
      const int qg = qh + 2 * sub;  // which 16B chunk holds this lane's 8 k's
      long a[4], b[4];
#pragma unroll
      for (int i = 0; i < 4; ++i) {
        const int ra = wr * 64 + i * 16 + fr;
        const int rb = wc * 64 + i * 16 + fr;
        a[i] = *(const long*)(sA + ra * BK + (qg ^ ((ra >> 1) & 3)) * 16 + w8);
        b[i] = *(const long*)(sB + rb * BK + (qg ^ ((rb >> 1) & 3)) * 16 + w8);
      }
#pragma unroll
      for (int i = 0; i < 4; ++i)
#pragma unroll
        for (int j = 0; j < 4; ++j)
          acc[i][j] = __builtin_amdgcn_mfma_f32_16x16x32_fp8_fp8(
              a[i], b[j], acc[i][j], 0, 0, 0);
    }
    __syncthreads();  // guard LDS overwrite next iter
  }

  // Epilogue. C/D layout (16x16 shapes, dtype-independent):
  // col = lane&15, row = (lane>>4)*4 + reg.
  const int rq = h * 4;
  float posPart = 0.0f;
  float colAcc[4] = {0.0f, 0.0f, 0.0f, 0.0f};
#pragma unroll
  for (int i = 0; i < 4; ++i) {
    const int rbase = rowBase + wr * 64 + i * 16 + rq;
    float rs[4] = {0.0f, 0.0f, 0.0f, 0.0f};
#pragma unroll
    for (int j = 0; j < 4; ++j) {
      const int colg = colBase + wc * 64 + j * 16 + fr;
      fp32x4 v = acc[i][j];
#pragma unroll
      for (int rg = 0; rg < 4; ++rg) {
        const int rowg = rbase + rg;
        const float sv = v[rg] * INV_T;
        float e = __expf(sv);
        if (diag && rowg == colg) e = 0.0f;  // exclude matrix diagonal exactly
        rs[rg] += e;
        colAcc[j] += e;
        if (colg == rowg + BS) posPart += sv;  // upper copy only; doubled later
      }
    }
    // row sums: reduce over the 16 columns (lanes differing in bits 0..3)
#pragma unroll
    for (int rg = 0; rg < 4; ++rg) {
      float s = rs[rg];
      s += __shfl_xor(s, 1);
      s += __shfl_xor(s, 2);
      s += __shfl_xor(s, 4);
      s += __shfl_xor(s, 8);
      if (fr == 0) atomicAdd(&den[rbase + rg], s);
    }
  }
  if (!diag) {
    // col sums (symmetric contribution): regs already summed; reduce lanes
    // differing in bits 4..5
#pragma unroll
    for (int j = 0; j < 4; ++j) {
      float c = colAcc[j];
      c += __shfl_xor(c, 16);
      c += __shfl_xor(c, 32);
      if (h == 0) atomicAdd(&den[colBase + wc * 64 + j * 16 + fr], c);
    }
  }
  posPart += __shfl_xor(posPart, 1);
  posPart += __shfl_xor(posPart, 2);
  posPart += __shfl_xor(posPart, 4);
  posPart += __shfl_xor(posPart, 8);
  posPart += __shfl_xor(posPart, 16);
  posPart += __shfl_xor(posPart, 32);
  if (lane == 0 && posPart != 0.0f) atomicAdd(posAcc, posPart);
}

__global__ __launch_bounds__(256) void finalize_k(
    const float* __restrict__ den, const float* __restrict__ posAcc,
    float* __restrict__ out) {
  const int t = threadIdx.x;
  float s = 0.0f;
  for (int i = t; i < NROW; i += 256) s += logf(den[i]);
#pragma unroll
  for (int off = 1; off < 64; off <<= 1) s += __shfl_xor(s, off);
  __shared__ float ws[4];
  if ((t & 63) == 0) ws[t >> 6] = s;
  __syncthreads();
  if (t == 0) {
    const float tot = ws[0] + ws[1] + ws[2] + ws[3];
    // each unordered positive pair was counted once -> double it
    out[0] = (tot - 2.0f * posAcc[0]) * (1.0f / (float)NROW);
  }
}

extern "C" void kernel_launch(void* const* d_in, const int* in_sizes, int n_in,
                              void* d_out, int out_size, void* d_ws, size_t ws_size,
                              hipStream_t stream) {
  const float* zi = (const float*)d_in[0];
  const float* zj = (const float*)d_in[1];
  float* out = (float*)d_out;

  u8* An = (u8*)d_ws;                                      // 4 MB fp8 normalized reps
  float* den = (float*)((char*)d_ws + (size_t)NROW * D);   // 8192 fp32
  float* posAcc = den + NROW;                              // 1 fp32

  normalize_k<<<NROW / 4, 256, 0, stream>>>(zi, zj, An, den, posAcc);
  gemm_expsum<<<NBLK, 256, 0, stream>>>(An, den, posAcc);
  finalize_k<<<1, 256, 0, stream>>>(den, posAcc, out);
}